// Round 10
// baseline (607.044 us; speedup 1.0000x reference)
//
#include <hip/hip_runtime.h>

// g2[b,c,h,w] = sum_d cost[b,d,h,w] * h1[b,c,h,w+d]   (w+d < W, else 0)
// B=4 C=32 H=256 W=512 D=48, fp32.
//
// v8 = v6 + distance-1 cost double-buffer + MASK-split. Nothing else.
//
// Constraints learned (measured, 4 rounds): this toolchain pins VGPR at
// 64 max regardless of launch_bounds (v0/v1/v2/v7b all 64 + spills when
// state>64). So: 2 channels/wave, no LDS, live state = win 16 + acc 8 +
// cv 2x16 = 56 + addr ~6 < 64. Spill tripwire: WRITE_SIZE must be
// exactly 65536 KB.
//
// Theory being tested: v3/v5/v6 all sit at 110-146us with every pipe
// <50% (VALU ~22%, HBM ~25%) -> latency-bound, convoyed waves: each
// group is a serial {4 cost loads -> drain -> ~100cy FMA} chain. The
// cv double-buffer overlaps group g's FMAs with g+1's loads (the one
// lever v2/v7b attempted but drowned in spills).
//   - no LDS, no barriers (v6 mechanism, conflicts measured 0).
//   - template<MASK>: wstart=0 half has max operand index 303<512 ->
//     zero masking on half the grid.
//   - explicit fmaf; nontemporal out stores (native vec type).

#define BB 4
#define CC 32
#define HH 256
#define WW 512
#define DDISP 48
#define HW (HH * WW)     // 131072
#define TW 256
#define NT 256

typedef float f32x4 __attribute__((ext_vector_type(4)));

// h1 quad load. Quads are 4-aligned and W%4==0 -> fully in or fully out.
template<bool MASK>
__device__ __forceinline__ void ldq(const float* __restrict__ row, int wq,
                                    float* __restrict__ dst)
{
    if (MASK) {
        int wc = wq > (WW - 4) ? (WW - 4) : wq;   // clamp keeps addr in-row
        float4 t = *(const float4*)(row + wc);
        bool ok = wq < WW;
        dst[0] = ok ? t.x : 0.f;
        dst[1] = ok ? t.y : 0.f;
        dst[2] = ok ? t.z : 0.f;
        dst[3] = ok ? t.w : 0.f;
    } else {
        float4 t = *(const float4*)(row + wq);
        dst[0] = t.x; dst[1] = t.y; dst[2] = t.z; dst[3] = t.w;
    }
}

template<bool MASK>
__device__ __forceinline__ void body(const float* __restrict__ h1,
                                     const float* __restrict__ cost,
                                     float* __restrict__ out,
                                     int b, int h, int cgrp, int wstart)
{
    const int lane = threadIdx.x & 63;
    const int wid  = threadIdx.x >> 6;           // 0..3
    const int c0   = (cgrp << 3) + (wid << 1);   // 2 channels per wave
    const int w0   = lane << 2;
    const int wq0  = wstart + w0;                // lane's first output w

    const float* r0 = h1 + (((size_t)(b * CC + c0    )) * HH + h) * WW;
    const float* r1 = h1 + (((size_t)(b * CC + c0 + 1)) * HH + h) * WW;

    float acc0[4] = {0.f, 0.f, 0.f, 0.f};
    float acc1[4] = {0.f, 0.f, 0.f, 0.f};

    // win[c][slot*4+k]: circular 2-quad window. Invariant at start of
    // group g: slot (g&1) = h1 quad at wq0+4g, slot ((g+1)&1) = wq0+4g+4.
    float win0[8], win1[8];
    ldq<false>(r0, wq0,     &win0[0]);           // wq0 <= 508: never OOB
    ldq<MASK >(r0, wq0 + 4, &win0[4]);           // wq0+4 can hit 512
    ldq<false>(r1, wq0,     &win1[0]);
    ldq<MASK >(r1, wq0 + 4, &win1[4]);

    const float* cp = cost + ((size_t)(b * DDISP) * HH + h) * WW + wq0;

    // cost double-buffer: group g consumes cv[g&1]; g+1's rows are issued
    // BEFORE g's FMAs. Fully unrolled -> all indices static.
    float cv[2][4][4];
#pragma unroll
    for (int dd = 0; dd < 4; ++dd) {
        float4 t = *(const float4*)(cp + (size_t)dd * HW);
        cv[0][dd][0] = t.x; cv[0][dd][1] = t.y;
        cv[0][dd][2] = t.z; cv[0][dd][3] = t.w;
    }

#pragma unroll
    for (int g = 0; g < 12; ++g) {
        const int cur = g & 1;
        const int nxt = cur ^ 1;
        if (g < 11) {
            // prefetch next group's 4 cost rows (independent of group g)
#pragma unroll
            for (int dd = 0; dd < 4; ++dd) {
                float4 t = *(const float4*)(cp + (size_t)(4 * (g + 1) + dd) * HW);
                cv[nxt][dd][0] = t.x; cv[nxt][dd][1] = t.y;
                cv[nxt][dd][2] = t.z; cv[nxt][dd][3] = t.w;
            }
        }
        // FMAs: group g covers d = 4g..4g+3; output j needs operand
        // wq0+4g+(dd+j), dd+j in 0..6 -> window quads [4g, 4g+7].
#pragma unroll
        for (int dd = 0; dd < 4; ++dd)
#pragma unroll
            for (int j = 0; j < 4; ++j) {
                const int o    = dd + j;               // 0..6
                const int slot = (cur + (o >> 2)) & 1;
                acc0[j] = __builtin_fmaf(cv[cur][dd][j],
                                         win0[slot * 4 + (o & 3)], acc0[j]);
                acc1[j] = __builtin_fmaf(cv[cur][dd][j],
                                         win1[slot * 4 + (o & 3)], acc1[j]);
            }
        if (g < 11) {
            // slide: slot (cur) [quad 4g] is dead after g's FMAs; overwrite
            // with quad 4g+8 (needed by group g+1).
            ldq<MASK>(r0, wq0 + 4 * g + 8, &win0[cur * 4]);
            ldq<MASK>(r1, wq0 + 4 * g + 8, &win1[cur * 4]);
        }
    }

    float* o0 = out + (((size_t)(b * CC + c0    )) * HH + h) * WW + wq0;
    float* o1 = out + (((size_t)(b * CC + c0 + 1)) * HH + h) * WW + wq0;
    f32x4 v0 = { acc0[0], acc0[1], acc0[2], acc0[3] };
    f32x4 v1 = { acc1[0], acc1[1], acc1[2], acc1[3] };
    __builtin_nontemporal_store(v0, (f32x4*)o0);
    __builtin_nontemporal_store(v1, (f32x4*)o1);
}

__global__ __launch_bounds__(NT, 4)
void dense_warp_kernel(const float* __restrict__ h1,
                       const float* __restrict__ cost,
                       float* __restrict__ out)
{
    const int blk    = blockIdx.x;
    const int wside  = blk & 1;
    const int h      = (blk >> 1) & (HH - 1);
    const int cgrp   = (blk >> 9) & 3;
    const int b      = blk >> 11;

    if (wside == 0) body<false>(h1, cost, out, b, h, cgrp, 0);
    else            body<true >(h1, cost, out, b, h, cgrp, TW);
}

extern "C" void kernel_launch(void* const* d_in, const int* in_sizes, int n_in,
                              void* d_out, int out_size, void* d_ws, size_t ws_size,
                              hipStream_t stream) {
    const float* h1   = (const float*)d_in[0];
    const float* cost = (const float*)d_in[1];
    float* out        = (float*)d_out;
    dim3 grid(BB * HH * 2 * 4);   // (b, cgrp, h, wside) = 8192
    dense_warp_kernel<<<grid, NT, 0, stream>>>(h1, cost, out);
}

// Round 12
// 240.251 us; speedup vs baseline: 2.5267x; 2.5267x over previous
//
#include <hip/hip_runtime.h>

// g2[b,c,h,w] = sum_d cost[b,d,h,w] * h1[b,c,h,w+d]   (w+d < W, else 0)
// B=4 C=32 H=256 W=512 D=48, fp32.
//
// v9 (resubmit; round 11 failed on container acquire — same infra
// signature as rounds 5-6, which ran fine on retry; kernel audited:
// static bounds, uniform barrier, no OOB, no capture violations).
//
// v9 = v3 (the measured best: 110us, VGPR 32, occ 72%, zero spill)
// + ONE change: distance-1 double-buffered cost prefetch.
//
// Hard constraint (measured 5x: v0/v1/v2/v7b/v8): allocator caps VGPR
// at 64; live state > ~60 floats => catastrophic scratch spill.
// v9 budget: acc 16 + cv[2] 32 + srcv 8 (transient) + addr ~6 = ~62.
// Spill tripwire: WRITE_SIZE must be exactly 65536 KB.
//
// Theory under test: v3/v5/v6 all sit at 110-146us with VALU ~22%,
// HBM ~25%, LDS-or-not irrelevant -> per-wave serial chain
// {4 cost loads -> vmcnt drain -> 128 FMA} is the limiter. Prefetch
// overlaps group g's FMAs with g+1's loads. First buffer issued before
// __syncthreads so the load hides under the staging drain.

#define BB 4
#define CC 32
#define CHB 16           // channels per block
#define HH 256
#define WW 512
#define DDISP 48
#define HW (HH * WW)     // 131072
#define TW 256
#define WROW 312         // 303 needed, quad-rounded + pad
#define NT 256

__global__ __launch_bounds__(NT, 4)
void dense_warp_kernel(const float* __restrict__ h1,
                       const float* __restrict__ cost,
                       float* __restrict__ out)
{
    __shared__ float h1s[CHB * WROW];   // 19968 B -> 8 blocks/CU

    const int blk    = blockIdx.x;
    const int wside  = blk & 1;
    const int h      = (blk >> 1) & (HH - 1);
    const int chalf  = (blk >> 9) & 1;
    const int b      = blk >> 10;
    const int wstart = wside * TW;
    const int tid    = threadIdx.x;

    const int lane = tid & 63;
    const int wid  = tid >> 6;        // 0..3 -> channel group within block
    const int c0   = wid << 2;        // 4 channels per wave
    const int w0   = lane << 2;       // 4 consecutive w per lane

    const float* cpg = cost + ((size_t)b * DDISP * HH + (size_t)h) * WW + wstart + w0;

    // cost double-buffer: group g consumes cv[g&1]. Buffer 0 is issued
    // BEFORE the barrier: its latency hides under the staging drain.
    float cv[2][4][4];
#pragma unroll
    for (int dd = 0; dd < 4; ++dd) {
        float4 t = *(const float4*)(cpg + (size_t)dd * HW);
        cv[0][dd][0] = t.x; cv[0][dd][1] = t.y;
        cv[0][dd][2] = t.z; cv[0][dd][3] = t.w;
    }

    // ---- stage h1[b, chalf*16 .. +15, h, wstart .. wstart+311] (zeros past W)
    {
        const float* src = h1 + (((size_t)b * CC + chalf * CHB) * HH + (size_t)h) * WW;
        for (int idx = tid; idx < CHB * 78; idx += NT) {   // 78 quads/row
            int r    = idx / 78;
            int q    = idx - r * 78;
            int col  = q << 2;
            int wsrc = wstart + col;
            float4 v = make_float4(0.f, 0.f, 0.f, 0.f);
            if (wsrc < WW) v = *(const float4*)(src + (size_t)r * HW + wsrc);
            *(float4*)(&h1s[r * WROW + col]) = v;
        }
    }
    __syncthreads();

    float acc[4][4];
#pragma unroll
    for (int c = 0; c < 4; ++c)
#pragma unroll
        for (int j = 0; j < 4; ++j) acc[c][j] = 0.f;

    const float* lbase = &h1s[c0 * WROW + w0];

    // Group g covers d = 4g..4g+3. For output j (0..3), operand index is
    // w0 + 4g + (dd+j), dd+j in 0..6 -> two LDS quads [4g, 4g+7] / channel.
#pragma unroll
    for (int g = 0; g < 12; ++g) {
        const int cur = g & 1;
        const int nxt = cur ^ 1;
        if (g < 11) {
            // prefetch next group's 4 cost rows (independent of group g)
#pragma unroll
            for (int dd = 0; dd < 4; ++dd) {
                float4 t = *(const float4*)(cpg + (size_t)(4 * (g + 1) + dd) * HW);
                cv[nxt][dd][0] = t.x; cv[nxt][dd][1] = t.y;
                cv[nxt][dd][2] = t.z; cv[nxt][dd][3] = t.w;
            }
        }
#pragma unroll
        for (int c = 0; c < 4; ++c) {
            const float* lp = lbase + c * WROW + 4 * g;
            float4 q0 = *(const float4*)(lp);
            float4 q1 = *(const float4*)(lp + 4);
            float srcv[8] = { q0.x, q0.y, q0.z, q0.w, q1.x, q1.y, q1.z, q1.w };
#pragma unroll
            for (int dd = 0; dd < 4; ++dd)
#pragma unroll
                for (int j = 0; j < 4; ++j)
                    acc[c][j] = __builtin_fmaf(cv[cur][dd][j], srcv[dd + j],
                                               acc[c][j]);
        }
    }

    float* outBase = out + (((size_t)b * CC + chalf * CHB) * HH + (size_t)h) * WW
                     + wstart + w0;
#pragma unroll
    for (int c = 0; c < 4; ++c) {
        float* op = outBase + (size_t)(c0 + c) * HW;
        *(float4*)op = make_float4(acc[c][0], acc[c][1], acc[c][2], acc[c][3]);
    }
}

extern "C" void kernel_launch(void* const* d_in, const int* in_sizes, int n_in,
                              void* d_out, int out_size, void* d_ws, size_t ws_size,
                              hipStream_t stream) {
    const float* h1   = (const float*)d_in[0];
    const float* cost = (const float*)d_in[1];
    float* out        = (float*)d_out;
    dim3 grid(BB * HH * 2 * 2);   // (b, chalf, h, w-half) = 4096
    dense_warp_kernel<<<grid, NT, 0, stream>>>(h1, cost, out);
}